// Round 1
// baseline (349.491 us; speedup 1.0000x reference)
//
#include <hip/hip_runtime.h>
#include <hip/hip_bf16.h>
#include <stdint.h>

// Problem constants
#define DIMS  2048
#define HEADS 16
#define HD    128
#define BATCH 2
#define SEQ   2048
#define MROWS (BATCH*SEQ)   // 4096
#define QKVN  (3*DIMS)      // 6144

using bf16x8 = __attribute__((ext_vector_type(8))) short;
using f32x4  = __attribute__((ext_vector_type(4))) float;
using u16x4  = __attribute__((ext_vector_type(4))) unsigned short;

__device__ __forceinline__ unsigned short f2b(float f){
    __hip_bfloat16 h = __float2bfloat16(f);
    return *reinterpret_cast<unsigned short*>(&h);
}
__device__ __forceinline__ float b2f(unsigned short u){
    __hip_bfloat16 h;
    *reinterpret_cast<unsigned short*>(&h) = u;
    return __bfloat162float(h);
}

// async global->LDS, 16B per lane. LDS dest must be wave-uniform base (+lane*16 implicit).
__device__ __forceinline__ void glds16(const void* g, void* l){
    __builtin_amdgcn_global_load_lds(
        (const __attribute__((address_space(1))) unsigned int*)g,
        (__attribute__((address_space(3))) unsigned int*)l, 16, 0, 0);
}

// ---------------- elementwise prep kernels ----------------

__global__ void k_f32bf16(const float* __restrict__ src, unsigned short* __restrict__ dst, int n4){
    int i = blockIdx.x*blockDim.x + threadIdx.x;
    if (i >= n4) return;
    const float4 v = reinterpret_cast<const float4*>(src)[i];
    u16x4 o = { f2b(v.x), f2b(v.y), f2b(v.z), f2b(v.w) };
    *reinterpret_cast<u16x4*>(dst + 4*(size_t)i) = o;
}

__global__ void k_cossin(const float* __restrict__ r, float* __restrict__ c, float* __restrict__ s, int n){
    int i = blockIdx.x*blockDim.x + threadIdx.x;
    if (i >= n) return;
    float v = r[i];
    c[i] = cosf(v);
    s[i] = sinf(v);
}

// RoPE in-place on Q and K sections of qkv [MROWS][6144] bf16
__global__ void k_rope(unsigned short* __restrict__ qkv,
                       const float* __restrict__ ct, const float* __restrict__ st){
    const int idx = blockIdx.x*blockDim.x + threadIdx.x;  // BATCH*SEQ*HEADS*64
    const int d = idx & 63;
    const int h = (idx >> 6) & (HEADS-1);
    const int l = (idx >> 10) & (SEQ-1);
    const int b = idx >> 21;
    const float c0 = ct[l*HD + d],      s0 = st[l*HD + d];
    const float c1 = ct[l*HD + d + 64], s1 = st[l*HD + d + 64];
    unsigned short* row = qkv + (size_t)(b*SEQ + l)*QKVN + h*HD;
    {   // Q
        float x1 = b2f(row[d]), x2 = b2f(row[d+64]);
        row[d]    = f2b(x1*c0 - x2*s0);
        row[d+64] = f2b(x2*c1 + x1*s1);
    }
    {   // K
        unsigned short* kr = row + DIMS;
        float x1 = b2f(kr[d]), x2 = b2f(kr[d+64]);
        kr[d]    = f2b(x1*c0 - x2*s0);
        kr[d+64] = f2b(x2*c1 + x1*s1);
    }
}

// V transpose: qkv V section [b][l][h*128+d] -> vt[(b*16+h)*128 + d][l]
__global__ void k_vtrans(const unsigned short* __restrict__ qkv, unsigned short* __restrict__ vt){
    __shared__ unsigned short t[64*68];     // pitch 68: 8B-aligned rows, odd-ish banks
    const int lt = blockIdx.x;              // l tile (64)
    const int dt = blockIdx.y;              // d tile (64)
    const int bh = blockIdx.z;
    const int b = bh >> 4, h = bh & 15;
    const int tid = threadIdx.x;
    const int l0 = lt << 6;
    #pragma unroll
    for (int it = 0; it < 4; ++it){
        const int c = tid + (it<<8);
        const int l = c >> 4;
        const int d4 = (c & 15) << 2;
        const u16x4 v = *reinterpret_cast<const u16x4*>(
            qkv + (size_t)(b*SEQ + l0 + l)*QKVN + 2*DIMS + h*HD + (dt<<6) + d4);
        *reinterpret_cast<u16x4*>(&t[l*68 + d4]) = v;
    }
    __syncthreads();
    #pragma unroll
    for (int it = 0; it < 4; ++it){
        const int c = tid + (it<<8);
        const int d = c >> 4;
        const int l4 = (c & 15) << 2;
        u16x4 o = { t[(l4+0)*68 + d], t[(l4+1)*68 + d], t[(l4+2)*68 + d], t[(l4+3)*68 + d] };
        *reinterpret_cast<u16x4*>(&vt[((size_t)bh*HD + (dt<<6) + d)*SEQ + l0 + l4]) = o;
    }
}

// ---------------- GEMM: C[M][N] = A[M][K] * B[N][K]^T  (m97 structure) ----------------
// A,B bf16 row-major (lda=ldb=K). FINAL=0: bf16 C. FINAL=1: f32 C + bias.
// LDS tiles swizzled: element (row,col) stored at col ^ ((row&7)<<3) (within 64-elem row),
// achieved via pre-swizzled global source (global_load_lds writes linearly).

template<int FINAL>
__global__ __launch_bounds__(256) void k_gemm_bt(
    const unsigned short* __restrict__ A, const unsigned short* __restrict__ B,
    void* __restrict__ C, const float* __restrict__ bias, int M, int N, int K)
{
    __shared__ unsigned short lA[128*64];
    __shared__ unsigned short lB[128*64];
    const int tid  = threadIdx.x;
    const int lane = tid & 63;
    const int wave = tid >> 6;

    const int nbx = N >> 7;
    const int nwg = gridDim.x;
    const int cpx = nwg >> 3;                 // nwg % 8 == 0 for all our launches
    const int bid = blockIdx.x;
    const int wg  = (bid & 7)*cpx + (bid >> 3);   // XCD-aware swizzle (bijective)
    const int m0 = (wg / nbx) << 7;
    const int n0 = (wg % nbx) << 7;

    const int wr = (wave >> 1) << 6;          // wave row offset in 128x128 tile
    const int wc = (wave & 1) << 6;

    f32x4 acc[4][4] = {};

    const int srow_base = (wave<<3) + (lane>>3);  // 0..31
    const int schunk = lane & 7;

    for (int k0 = 0; k0 < K; k0 += 64){
        #pragma unroll
        for (int i = 0; i < 4; ++i){
            const int row  = (i<<5) + srow_base;
            const int scol = k0 + ((schunk ^ (row & 7)) << 3);  // pre-swizzled source
            glds16(A + (size_t)(m0 + row)*K + scol, &lA[((i<<5) + (wave<<3)) << 6]);
            glds16(B + (size_t)(n0 + row)*K + scol, &lB[((i<<5) + (wave<<3)) << 6]);
        }
        __syncthreads();
        #pragma unroll
        for (int ks = 0; ks < 2; ++ks){
            bf16x8 af[4], bfr[4];
            const int colbase = (ks<<5) + ((lane>>4)<<3);
            #pragma unroll
            for (int mi = 0; mi < 4; ++mi){
                const int row = wr + (mi<<4) + (lane & 15);
                af[mi] = *reinterpret_cast<const bf16x8*>(&lA[(row<<6) + (colbase ^ ((row&7)<<3))]);
            }
            #pragma unroll
            for (int ni = 0; ni < 4; ++ni){
                const int row = wc + (ni<<4) + (lane & 15);
                bfr[ni] = *reinterpret_cast<const bf16x8*>(&lB[(row<<6) + (colbase ^ ((row&7)<<3))]);
            }
            #pragma unroll
            for (int mi = 0; mi < 4; ++mi)
                #pragma unroll
                for (int ni = 0; ni < 4; ++ni)
                    acc[mi][ni] = __builtin_amdgcn_mfma_f32_16x16x32_bf16(af[mi], bfr[ni], acc[mi][ni], 0, 0, 0);
        }
        __syncthreads();
    }

    // epilogue: D layout col=lane&15, row=(lane>>4)*4+r
    const int r0 = (lane >> 4) << 2;
    const int cn = lane & 15;
    #pragma unroll
    for (int mi = 0; mi < 4; ++mi)
        #pragma unroll
        for (int r = 0; r < 4; ++r){
            const int gm = m0 + wr + (mi<<4) + r0 + r;
            #pragma unroll
            for (int ni = 0; ni < 4; ++ni){
                const int gn = n0 + wc + (ni<<4) + cn;
                const float v = acc[mi][ni][r];
                if (FINAL)
                    reinterpret_cast<float*>(C)[(size_t)gm*N + gn] = v + bias[gn];
                else
                    reinterpret_cast<unsigned short*>(C)[(size_t)gm*N + gn] = f2b(v);
            }
        }
}

// ---------------- flash attention ----------------
// grid: (qtile=16, bh=32), block 512 (8 waves). Each wave: 16 q-rows.
// KV tile 64. lK [64][128], lV (=V^T) [128][64], lP per-wave [16][64]; all XOR-swizzled.

__global__ __launch_bounds__(512) void k_attn(
    const unsigned short* __restrict__ qkv, const unsigned short* __restrict__ vt,
    unsigned short* __restrict__ aout)
{
    __shared__ unsigned short lK[64*128];
    __shared__ unsigned short lV[128*64];
    __shared__ unsigned short lP[8*16*64];

    const int tid  = threadIdx.x;
    const int lane = tid & 63;
    const int wave = tid >> 6;
    const int bh = blockIdx.y;
    const int b = bh >> 4, h = bh & 15;
    const int q0 = (blockIdx.x << 7) + (wave << 4);

    // Q fragments in registers, pre-scaled by 1/sqrt(HD)
    bf16x8 qf[4];
    {
        const unsigned short* qp = qkv + (size_t)(b*SEQ + q0 + (lane & 15))*QKVN + h*HD;
        #pragma unroll
        for (int ks = 0; ks < 4; ++ks){
            bf16x8 tv = *reinterpret_cast<const bf16x8*>(qp + (ks<<5) + ((lane>>4)<<3));
            #pragma unroll
            for (int j = 0; j < 8; ++j){
                unsigned short u = (unsigned short)tv[j];
                tv[j] = (short)f2b(b2f(u) * 0.08838834764831845f);
            }
            qf[ks] = tv;
        }
    }

    float m_run[4] = {-3e38f,-3e38f,-3e38f,-3e38f};
    float l_run[4] = {0.f,0.f,0.f,0.f};
    f32x4 acc[8] = {};

    const unsigned short* Kb = qkv + (size_t)b*SEQ*QKVN + DIMS + h*HD;
    const unsigned short* Vb = vt + (size_t)bh*HD*SEQ;

    const int kRow   = (wave<<2) + (lane>>4);  // 0..31 (+i*32)
    const int kChunk = lane & 15;
    const int vRow   = (wave<<3) + (lane>>3);  // 0..63 (+i*64)
    const int vChunk = lane & 7;

    for (int kv0 = 0; kv0 < SEQ; kv0 += 64){
        #pragma unroll
        for (int i = 0; i < 2; ++i){
            const int row = (i<<5) + kRow;
            glds16(Kb + (size_t)(kv0 + row)*QKVN + ((kChunk ^ (row & 7)) << 3),
                   &lK[((i<<5) + (wave<<2)) << 7]);
            const int d = (i<<6) + vRow;
            glds16(Vb + (size_t)d*SEQ + kv0 + ((vChunk ^ (d & 7)) << 3),
                   &lV[((i<<6) + (wave<<3)) << 6]);
        }
        __syncthreads();

        // S = (Q*scale) K^T   (4 key-subtiles of 16)
        f32x4 sacc[4] = {};
        const int colhi = (lane>>4) << 3;
        #pragma unroll
        for (int nt = 0; nt < 4; ++nt){
            const int row = (nt<<4) + (lane & 15);
            #pragma unroll
            for (int ks = 0; ks < 4; ++ks){
                const int col = ((ks<<5) + colhi) ^ ((row & 7) << 3);
                bf16x8 kf = *reinterpret_cast<const bf16x8*>(&lK[(row<<7) + col]);
                sacc[nt] = __builtin_amdgcn_mfma_f32_16x16x32_bf16(qf[ks], kf, sacc[nt], 0, 0, 0);
            }
        }

        // online softmax (row = (lane>>4)*4 + r, spread over 16 lanes)
        float tmax[4];
        #pragma unroll
        for (int r = 0; r < 4; ++r)
            tmax[r] = fmaxf(fmaxf(sacc[0][r], sacc[1][r]), fmaxf(sacc[2][r], sacc[3][r]));
        #pragma unroll
        for (int mk = 1; mk < 16; mk <<= 1)
            #pragma unroll
            for (int r = 0; r < 4; ++r)
                tmax[r] = fmaxf(tmax[r], __shfl_xor(tmax[r], mk));
        float al[4];
        #pragma unroll
        for (int r = 0; r < 4; ++r){
            const float mn = fmaxf(m_run[r], tmax[r]);
            al[r] = __expf(m_run[r] - mn);
            m_run[r] = mn;
        }
        float tsum[4] = {0.f,0.f,0.f,0.f};
        #pragma unroll
        for (int nt = 0; nt < 4; ++nt)
            #pragma unroll
            for (int r = 0; r < 4; ++r){
                const float p = __expf(sacc[nt][r] - m_run[r]);
                sacc[nt][r] = p;
                tsum[r] += p;
            }
        #pragma unroll
        for (int mk = 1; mk < 16; mk <<= 1)
            #pragma unroll
            for (int r = 0; r < 4; ++r)
                tsum[r] += __shfl_xor(tsum[r], mk);
        #pragma unroll
        for (int r = 0; r < 4; ++r)
            l_run[r] = l_run[r]*al[r] + tsum[r];
        #pragma unroll
        for (int di = 0; di < 8; ++di)
            #pragma unroll
            for (int r = 0; r < 4; ++r)
                acc[di][r] *= al[r];

        // P -> per-wave LDS (bf16), swizzled; then read back as A-fragments
        const int pbase = wave << 10;
        #pragma unroll
        for (int nt = 0; nt < 4; ++nt)
            #pragma unroll
            for (int r = 0; r < 4; ++r){
                const int prow = ((lane>>4)<<2) + r;
                const int pcol = (nt<<4) + (lane & 15);
                lP[pbase + (prow<<6) + (pcol ^ ((prow&7)<<3))] = f2b(sacc[nt][r]);
            }
        bf16x8 pf[2];
        {
            const int prow = lane & 15;
            #pragma unroll
            for (int kk = 0; kk < 2; ++kk){
                const int col = ((kk<<5) + colhi) ^ ((prow&7)<<3);
                pf[kk] = *reinterpret_cast<const bf16x8*>(&lP[pbase + (prow<<6) + col]);
            }
        }
        // O += P V
        #pragma unroll
        for (int di = 0; di < 8; ++di){
            const int vrow = (di<<4) + (lane & 15);
            #pragma unroll
            for (int kk = 0; kk < 2; ++kk){
                const int col = ((kk<<5) + colhi) ^ ((vrow&7)<<3);
                bf16x8 vf = *reinterpret_cast<const bf16x8*>(&lV[(vrow<<6) + col]);
                acc[di] = __builtin_amdgcn_mfma_f32_16x16x32_bf16(pf[kk], vf, acc[di], 0, 0, 0);
            }
        }
        __syncthreads();
    }

    #pragma unroll
    for (int di = 0; di < 8; ++di)
        #pragma unroll
        for (int r = 0; r < 4; ++r){
            const int qrow = q0 + ((lane>>4)<<2) + r;
            const int col  = h*HD + (di<<4) + (lane & 15);
            aout[(size_t)(b*SEQ + qrow)*DIMS + col] = f2b(acc[di][r] / l_run[r]);
        }
}

// ---------------- launcher ----------------

extern "C" void kernel_launch(void* const* d_in, const int* in_sizes, int n_in,
                              void* d_out, int out_size, void* d_ws, size_t ws_size,
                              hipStream_t stream)
{
    const float* x    = (const float*)d_in[0];
    const float* rope = (const float*)d_in[1];
    const float* wq   = (const float*)d_in[2];
    const float* wk   = (const float*)d_in[3];
    const float* wv   = (const float*)d_in[4];
    const float* wo   = (const float*)d_in[5];
    const float* bo   = (const float*)d_in[6];
    float* out = (float*)d_out;

    char* ws = (char*)d_ws;
    // layout (bytes); attn_out aliases x_bf (dead after QKV GEMM); vt aliases wqkv (dead after QKV GEMM)
    unsigned short* x_bf   = (unsigned short*)(ws + 0);            // 16.8 MB
    unsigned short* wqkv   = (unsigned short*)(ws + 16777216);     // 25.2 MB
    unsigned short* wo_bf  = (unsigned short*)(ws + 41943040);     // 8.4 MB
    float*          cos_t  = (float*)(ws + 50331648);              // 1 MB
    float*          sin_t  = (float*)(ws + 51380224);              // 1 MB
    unsigned short* qkv    = (unsigned short*)(ws + 52428800);     // 50.3 MB  (ends ~98 MB)
    unsigned short* vt     = (unsigned short*)(ws + 16777216);     // alias wqkv
    unsigned short* a_out  = (unsigned short*)(ws + 0);            // alias x_bf

    // 1. conversions
    k_f32bf16<<<8192, 256, 0, stream>>>(x,  x_bf,              2097152);
    k_f32bf16<<<4096, 256, 0, stream>>>(wq, wqkv,              1048576);
    k_f32bf16<<<4096, 256, 0, stream>>>(wk, wqkv + 4194304,    1048576);
    k_f32bf16<<<4096, 256, 0, stream>>>(wv, wqkv + 8388608,    1048576);
    k_f32bf16<<<4096, 256, 0, stream>>>(wo, wo_bf,             1048576);
    k_cossin <<<1024, 256, 0, stream>>>(rope, cos_t, sin_t, SEQ*HD);

    // 2. QKV projection: [4096,2048] x [6144,2048]^T -> qkv [4096,6144] bf16
    k_gemm_bt<0><<<(MROWS/128)*(QKVN/128), 256, 0, stream>>>(x_bf, wqkv, qkv, nullptr, MROWS, QKVN, DIMS);

    // 3. RoPE in place on Q,K
    k_rope<<<16384, 256, 0, stream>>>(qkv, cos_t, sin_t);

    // 4. V transpose -> vt [bh*128 + d][l]
    k_vtrans<<<dim3(SEQ/64, HD/64, BATCH*HEADS), 256, 0, stream>>>(qkv, vt);

    // 5. attention -> a_out [4096,2048] bf16
    k_attn<<<dim3(SEQ/128, BATCH*HEADS), 512, 0, stream>>>(qkv, vt, a_out);

    // 6. output projection + bias -> f32 out
    k_gemm_bt<1><<<(MROWS/128)*(DIMS/128), 256, 0, stream>>>(a_out, wo_bf, out, bo, MROWS, DIMS, DIMS);
}

// Round 2
// 309.799 us; speedup vs baseline: 1.1281x; 1.1281x over previous
//
#include <hip/hip_runtime.h>
#include <hip/hip_bf16.h>
#include <stdint.h>

// Problem constants
#define DIMS  2048
#define HEADS 16
#define HD    128
#define BATCH 2
#define SEQ   2048
#define MROWS (BATCH*SEQ)   // 4096
#define QKVN  (3*DIMS)      // 6144

using bf16x8 = __attribute__((ext_vector_type(8))) short;
using f32x4  = __attribute__((ext_vector_type(4))) float;
using f32x16 = __attribute__((ext_vector_type(16))) float;
using u16x4  = __attribute__((ext_vector_type(4))) unsigned short;

__device__ __forceinline__ unsigned short f2b(float f){
    __hip_bfloat16 h = __float2bfloat16(f);
    return *reinterpret_cast<unsigned short*>(&h);
}
__device__ __forceinline__ float b2f(unsigned short u){
    __hip_bfloat16 h;
    *reinterpret_cast<unsigned short*>(&h) = u;
    return __bfloat162float(h);
}
__device__ __forceinline__ unsigned int pkbf(float lo, float hi){
    return (unsigned int)f2b(lo) | ((unsigned int)f2b(hi) << 16);
}

// async global->LDS, 16B per lane. LDS dest must be wave-uniform base (+lane*16 implicit).
__device__ __forceinline__ void glds16(const void* g, void* l){
    __builtin_amdgcn_global_load_lds(
        (const __attribute__((address_space(1))) unsigned int*)g,
        (__attribute__((address_space(3))) unsigned int*)l, 16, 0, 0);
}

// ---------------- elementwise prep kernels ----------------

__global__ void k_f32bf16(const float* __restrict__ src, unsigned short* __restrict__ dst, int n4){
    int i = blockIdx.x*blockDim.x + threadIdx.x;
    if (i >= n4) return;
    const float4 v = reinterpret_cast<const float4*>(src)[i];
    u16x4 o = { f2b(v.x), f2b(v.y), f2b(v.z), f2b(v.w) };
    *reinterpret_cast<u16x4*>(dst + 4*(size_t)i) = o;
}

__global__ void k_cossin(const float* __restrict__ r, float* __restrict__ c, float* __restrict__ s, int n){
    int i = blockIdx.x*blockDim.x + threadIdx.x;
    if (i >= n) return;
    float v = r[i];
    c[i] = cosf(v);
    s[i] = sinf(v);
}

// RoPE in-place on Q and K sections of qkv [MROWS][6144] bf16
__global__ void k_rope(unsigned short* __restrict__ qkv,
                       const float* __restrict__ ct, const float* __restrict__ st){
    const int idx = blockIdx.x*blockDim.x + threadIdx.x;  // BATCH*SEQ*HEADS*64
    const int d = idx & 63;
    const int h = (idx >> 6) & (HEADS-1);
    const int l = (idx >> 10) & (SEQ-1);
    const int b = idx >> 21;
    const float c0 = ct[l*HD + d],      s0 = st[l*HD + d];
    const float c1 = ct[l*HD + d + 64], s1 = st[l*HD + d + 64];
    unsigned short* row = qkv + (size_t)(b*SEQ + l)*QKVN + h*HD;
    {   // Q
        float x1 = b2f(row[d]), x2 = b2f(row[d+64]);
        row[d]    = f2b(x1*c0 - x2*s0);
        row[d+64] = f2b(x2*c1 + x1*s1);
    }
    {   // K
        unsigned short* kr = row + DIMS;
        float x1 = b2f(kr[d]), x2 = b2f(kr[d+64]);
        kr[d]    = f2b(x1*c0 - x2*s0);
        kr[d+64] = f2b(x2*c1 + x1*s1);
    }
}

// V transpose: qkv V section [b][l][h*128+d] -> vt[(b*16+h)*128 + d][l]
__global__ void k_vtrans(const unsigned short* __restrict__ qkv, unsigned short* __restrict__ vt){
    __shared__ unsigned short t[64*68];
    const int lt = blockIdx.x;
    const int dt = blockIdx.y;
    const int bh = blockIdx.z;
    const int b = bh >> 4, h = bh & 15;
    const int tid = threadIdx.x;
    const int l0 = lt << 6;
    #pragma unroll
    for (int it = 0; it < 4; ++it){
        const int c = tid + (it<<8);
        const int l = c >> 4;
        const int d4 = (c & 15) << 2;
        const u16x4 v = *reinterpret_cast<const u16x4*>(
            qkv + (size_t)(b*SEQ + l0 + l)*QKVN + 2*DIMS + h*HD + (dt<<6) + d4);
        *reinterpret_cast<u16x4*>(&t[l*68 + d4]) = v;
    }
    __syncthreads();
    #pragma unroll
    for (int it = 0; it < 4; ++it){
        const int c = tid + (it<<8);
        const int d = c >> 4;
        const int l4 = (c & 15) << 2;
        u16x4 o = { t[(l4+0)*68 + d], t[(l4+1)*68 + d], t[(l4+2)*68 + d], t[(l4+3)*68 + d] };
        *reinterpret_cast<u16x4*>(&vt[((size_t)bh*HD + (dt<<6) + d)*SEQ + l0 + l4]) = o;
    }
}

// ---------------- GEMM: C[M][N] = A[M][K] * B[N][K]^T  (m97 structure) ----------------

template<int FINAL>
__global__ __launch_bounds__(256) void k_gemm_bt(
    const unsigned short* __restrict__ A, const unsigned short* __restrict__ B,
    void* __restrict__ C, const float* __restrict__ bias, int M, int N, int K)
{
    __shared__ unsigned short lA[128*64];
    __shared__ unsigned short lB[128*64];
    const int tid  = threadIdx.x;
    const int lane = tid & 63;
    const int wave = tid >> 6;

    const int nbx = N >> 7;
    const int nwg = gridDim.x;
    const int cpx = nwg >> 3;
    const int bid = blockIdx.x;
    const int wg  = (bid & 7)*cpx + (bid >> 3);
    const int m0 = (wg / nbx) << 7;
    const int n0 = (wg % nbx) << 7;

    const int wr = (wave >> 1) << 6;
    const int wc = (wave & 1) << 6;

    f32x4 acc[4][4] = {};

    const int srow_base = (wave<<3) + (lane>>3);
    const int schunk = lane & 7;

    for (int k0 = 0; k0 < K; k0 += 64){
        #pragma unroll
        for (int i = 0; i < 4; ++i){
            const int row  = (i<<5) + srow_base;
            const int scol = k0 + ((schunk ^ (row & 7)) << 3);
            glds16(A + (size_t)(m0 + row)*K + scol, &lA[((i<<5) + (wave<<3)) << 6]);
            glds16(B + (size_t)(n0 + row)*K + scol, &lB[((i<<5) + (wave<<3)) << 6]);
        }
        __syncthreads();
        #pragma unroll
        for (int ks = 0; ks < 2; ++ks){
            bf16x8 af[4], bfr[4];
            const int colbase = (ks<<5) + ((lane>>4)<<3);
            #pragma unroll
            for (int mi = 0; mi < 4; ++mi){
                const int row = wr + (mi<<4) + (lane & 15);
                af[mi] = *reinterpret_cast<const bf16x8*>(&lA[(row<<6) + (colbase ^ ((row&7)<<3))]);
            }
            #pragma unroll
            for (int ni = 0; ni < 4; ++ni){
                const int row = wc + (ni<<4) + (lane & 15);
                bfr[ni] = *reinterpret_cast<const bf16x8*>(&lB[(row<<6) + (colbase ^ ((row&7)<<3))]);
            }
            #pragma unroll
            for (int mi = 0; mi < 4; ++mi)
                #pragma unroll
                for (int ni = 0; ni < 4; ++ni)
                    acc[mi][ni] = __builtin_amdgcn_mfma_f32_16x16x32_bf16(af[mi], bfr[ni], acc[mi][ni], 0, 0, 0);
        }
        __syncthreads();
    }

    const int r0 = (lane >> 4) << 2;
    const int cn = lane & 15;
    #pragma unroll
    for (int mi = 0; mi < 4; ++mi)
        #pragma unroll
        for (int r = 0; r < 4; ++r){
            const int gm = m0 + wr + (mi<<4) + r0 + r;
            #pragma unroll
            for (int ni = 0; ni < 4; ++ni){
                const int gn = n0 + wc + (ni<<4) + cn;
                const float v = acc[mi][ni][r];
                if (FINAL)
                    reinterpret_cast<float*>(C)[(size_t)gm*N + gn] = v + bias[gn];
                else
                    reinterpret_cast<unsigned short*>(C)[(size_t)gm*N + gn] = f2b(v);
            }
        }
}

// ---------------- flash attention, swapped-operand 32x32 structure ----------------
// grid: (SEQ/256=8, bh=32), block 512 (8 waves x 32 q-rows).
// QK^T: S = mfma(K, Q)  -> S[kv][q], q = lane&31 (softmax per-lane).
// PV:   O^T = mfma(V^T, P) -> O[d][q], rescale per-lane.
// K/V double-buffered LDS, XOR-swizzled (chunk ^= row&7), staged via pre-swizzled source.

union U8 { unsigned int w[4]; bf16x8 v; };

__global__ __launch_bounds__(512, 2) void k_attn(
    const unsigned short* __restrict__ qkv, const unsigned short* __restrict__ vt,
    unsigned short* __restrict__ aout)
{
    __shared__ unsigned short lK[2][64*128];   // [kv][d], swizzled
    __shared__ unsigned short lV[2][128*64];   // [d][kv], swizzled
    __shared__ unsigned short lO[8*32*132];    // per-wave epilogue transpose (pitch 132 elems = 264B)

    const int tid  = threadIdx.x;
    const int lane = tid & 63;
    const int wave = tid >> 6;
    const int lq   = lane & 31;
    const int hi   = lane >> 5;
    const int bh = blockIdx.y;
    const int b = bh >> 4, h = bh & 15;
    const int q0w = (blockIdx.x << 8) + (wave << 5);

    const unsigned short* Kb = qkv + (size_t)b*SEQ*QKVN + DIMS + h*HD;
    const unsigned short* Vb = vt + (size_t)bh*HD*SEQ;

    // Q fragments (B-operand layout: col=q=lane&31, k = hi*8+j), pre-scaled by log2e/sqrt(HD)
    bf16x8 qf[8];
    {
        const float qscale = 0.08838834764831845f * 1.4426950408889634f;
        const unsigned short* qp = qkv + (size_t)(b*SEQ + q0w + lq)*QKVN + h*HD + (hi<<3);
        #pragma unroll
        for (int ks = 0; ks < 8; ++ks){
            bf16x8 tv = *reinterpret_cast<const bf16x8*>(qp + (ks<<4));
            #pragma unroll
            for (int j = 0; j < 8; ++j)
                tv[j] = (short)f2b(b2f((unsigned short)tv[j]) * qscale);
            qf[ks] = tv;
        }
    }

    float m_run = -3e38f, l_run = 0.f;
    f32x16 oacc[4] = {};

    #define STAGE(pb, kv0) do { \
        _Pragma("unroll") \
        for (int i = 0; i < 2; ++i){ \
            const int kr = (wave<<3) + (i<<2) + (lane>>4); \
            glds16(Kb + (size_t)((kv0) + kr)*QKVN + (((lane&15) ^ (kr&7))<<3), \
                   &lK[pb][((wave<<3) + (i<<2))<<7]); \
            const int dr = (wave<<4) + (i<<3) + (lane>>3); \
            glds16(Vb + (size_t)dr*SEQ + (kv0) + (((lane&7) ^ (dr&7))<<3), \
                   &lV[pb][((wave<<4) + (i<<3))<<6]); \
        } \
    } while(0)

    int buf = 0;
    STAGE(0, 0);
    __syncthreads();

    for (int t = 0; t < SEQ/64; ++t){
        if (t < SEQ/64 - 1) STAGE(buf^1, (t+1)*64);

        const unsigned short* Kbuf = &lK[buf][0];
        const unsigned short* Vbuf = &lV[buf][0];

        // ---- S = K * Q  (S[kv][q]) ----
        f32x16 st0 = {}, st1 = {};
        #pragma unroll
        for (int ks = 0; ks < 8; ++ks){
            const int col = (((ks<<1) + hi) ^ (lq & 7)) << 3;
            bf16x8 k0 = *reinterpret_cast<const bf16x8*>(&Kbuf[(lq<<7) + col]);
            bf16x8 k1 = *reinterpret_cast<const bf16x8*>(&Kbuf[((32+lq)<<7) + col]);
            st0 = __builtin_amdgcn_mfma_f32_32x32x16_bf16(k0, qf[ks], st0, 0, 0, 0);
            st1 = __builtin_amdgcn_mfma_f32_32x32x16_bf16(k1, qf[ks], st1, 0, 0, 0);
        }

        // ---- online softmax (exp2 domain), per-lane column q ----
        float tmax = st0[0];
        #pragma unroll
        for (int r = 1; r < 16; ++r) tmax = fmaxf(tmax, st0[r]);
        #pragma unroll
        for (int r = 0; r < 16; ++r) tmax = fmaxf(tmax, st1[r]);
        tmax = fmaxf(tmax, __shfl_xor(tmax, 32));
        const float mnew = fmaxf(m_run, tmax);
        const float al = __builtin_amdgcn_exp2f(m_run - mnew);
        m_run = mnew;
        float tsum = 0.f;
        #pragma unroll
        for (int r = 0; r < 16; ++r){ float p = __builtin_amdgcn_exp2f(st0[r] - mnew); st0[r] = p; tsum += p; }
        #pragma unroll
        for (int r = 0; r < 16; ++r){ float p = __builtin_amdgcn_exp2f(st1[r] - mnew); st1[r] = p; tsum += p; }
        tsum += __shfl_xor(tsum, 32);
        l_run = l_run*al + tsum;
        #pragma unroll
        for (int dt = 0; dt < 4; ++dt) oacc[dt] *= al;

        // ---- P -> B-fragments (col=q, k=kv), via pack + lane^32 exchange ----
        bf16x8 pf[4];
        #define MAKEPF(dA, dB, SV) do { \
            unsigned int a0 = pkbf(SV[0],SV[1]),  b0 = pkbf(SV[2],SV[3]); \
            unsigned int c0 = pkbf(SV[4],SV[5]),  d0 = pkbf(SV[6],SV[7]); \
            unsigned int a1 = pkbf(SV[8],SV[9]),  b1 = pkbf(SV[10],SV[11]); \
            unsigned int c1 = pkbf(SV[12],SV[13]),d1 = pkbf(SV[14],SV[15]); \
            unsigned int ax0 = __shfl_xor(a0,32), bx0 = __shfl_xor(b0,32); \
            unsigned int cx0 = __shfl_xor(c0,32), dx0 = __shfl_xor(d0,32); \
            unsigned int ax1 = __shfl_xor(a1,32), bx1 = __shfl_xor(b1,32); \
            unsigned int cx1 = __shfl_xor(c1,32), dx1 = __shfl_xor(d1,32); \
            U8 u; \
            u.w[0] = hi ? cx0 : a0;  u.w[1] = hi ? dx0 : b0; \
            u.w[2] = hi ? c0 : ax0;  u.w[3] = hi ? d0 : bx0; \
            dA = u.v; \
            u.w[0] = hi ? cx1 : a1;  u.w[1] = hi ? dx1 : b1; \
            u.w[2] = hi ? c1 : ax1;  u.w[3] = hi ? d1 : bx1; \
            dB = u.v; \
        } while(0)
        MAKEPF(pf[0], pf[1], st0);
        MAKEPF(pf[2], pf[3], st1);
        #undef MAKEPF

        // ---- O^T += V^T * P ----
        #pragma unroll
        for (int dt = 0; dt < 4; ++dt){
            const int rowv = (dt<<5) + lq;
            #pragma unroll
            for (int f = 0; f < 4; ++f){
                const int col = (((f<<1) + hi) ^ (lq & 7)) << 3;
                bf16x8 vf = *reinterpret_cast<const bf16x8*>(&Vbuf[(rowv<<6) + col]);
                oacc[dt] = __builtin_amdgcn_mfma_f32_32x32x16_bf16(vf, pf[f], oacc[dt], 0, 0, 0);
            }
        }

        __syncthreads();
        buf ^= 1;
    }
    #undef STAGE

    // ---- epilogue: O^T -> per-wave LDS transpose -> coalesced global ----
    const float rl = 1.0f / l_run;
    unsigned short* oL = lO + wave*(32*132);
    #pragma unroll
    for (int dt = 0; dt < 4; ++dt)
        #pragma unroll
        for (int g = 0; g < 4; ++g){
            u16x4 w = { f2b(oacc[dt][g*4+0]*rl), f2b(oacc[dt][g*4+1]*rl),
                        f2b(oacc[dt][g*4+2]*rl), f2b(oacc[dt][g*4+3]*rl) };
            *reinterpret_cast<u16x4*>(&oL[lq*132 + (dt<<5) + (hi<<2) + (g<<3)]) = w;
        }
    #pragma unroll
    for (int i = 0; i < 16; ++i){
        const int q = (i<<1) + hi;
        u16x4 w = *reinterpret_cast<const u16x4*>(&oL[q*132 + (lq<<2)]);
        *reinterpret_cast<u16x4*>(&aout[(size_t)(b*SEQ + q0w + q)*DIMS + h*HD + (lq<<2)]) = w;
    }
}

// ---------------- launcher ----------------

extern "C" void kernel_launch(void* const* d_in, const int* in_sizes, int n_in,
                              void* d_out, int out_size, void* d_ws, size_t ws_size,
                              hipStream_t stream)
{
    const float* x    = (const float*)d_in[0];
    const float* rope = (const float*)d_in[1];
    const float* wq   = (const float*)d_in[2];
    const float* wk   = (const float*)d_in[3];
    const float* wv   = (const float*)d_in[4];
    const float* wo   = (const float*)d_in[5];
    const float* bo   = (const float*)d_in[6];
    float* out = (float*)d_out;

    char* ws = (char*)d_ws;
    unsigned short* x_bf   = (unsigned short*)(ws + 0);            // 16.8 MB
    unsigned short* wqkv   = (unsigned short*)(ws + 16777216);     // 25.2 MB
    unsigned short* wo_bf  = (unsigned short*)(ws + 41943040);     // 8.4 MB
    float*          cos_t  = (float*)(ws + 50331648);              // 1 MB
    float*          sin_t  = (float*)(ws + 51380224);              // 1 MB
    unsigned short* qkv    = (unsigned short*)(ws + 52428800);     // 50.3 MB
    unsigned short* vt     = (unsigned short*)(ws + 16777216);     // alias wqkv
    unsigned short* a_out  = (unsigned short*)(ws + 0);            // alias x_bf

    k_f32bf16<<<8192, 256, 0, stream>>>(x,  x_bf,              2097152);
    k_f32bf16<<<4096, 256, 0, stream>>>(wq, wqkv,              1048576);
    k_f32bf16<<<4096, 256, 0, stream>>>(wk, wqkv + 4194304,    1048576);
    k_f32bf16<<<4096, 256, 0, stream>>>(wv, wqkv + 8388608,    1048576);
    k_f32bf16<<<4096, 256, 0, stream>>>(wo, wo_bf,             1048576);
    k_cossin <<<1024, 256, 0, stream>>>(rope, cos_t, sin_t, SEQ*HD);

    k_gemm_bt<0><<<(MROWS/128)*(QKVN/128), 256, 0, stream>>>(x_bf, wqkv, qkv, nullptr, MROWS, QKVN, DIMS);

    k_rope<<<16384, 256, 0, stream>>>(qkv, cos_t, sin_t);

    k_vtrans<<<dim3(SEQ/64, HD/64, BATCH*HEADS), 256, 0, stream>>>(qkv, vt);

    k_attn<<<dim3(SEQ/256, BATCH*HEADS), 512, 0, stream>>>(qkv, vt, a_out);

    k_gemm_bt<1><<<(MROWS/128)*(DIMS/128), 256, 0, stream>>>(a_out, wo_bf, out, bo, MROWS, DIMS, DIMS);
}

// Round 3
// 308.734 us; speedup vs baseline: 1.1320x; 1.0035x over previous
//
#include <hip/hip_runtime.h>
#include <hip/hip_bf16.h>
#include <stdint.h>

// Problem constants
#define DIMS  2048
#define HEADS 16
#define HD    128
#define BATCH 2
#define SEQ   2048
#define MROWS (BATCH*SEQ)   // 4096
#define QKVN  (3*DIMS)      // 6144

using bf16x8 = __attribute__((ext_vector_type(8))) short;
using f32x4  = __attribute__((ext_vector_type(4))) float;
using f32x16 = __attribute__((ext_vector_type(16))) float;
using u16x4  = __attribute__((ext_vector_type(4))) unsigned short;

__device__ __forceinline__ unsigned short f2b(float f){
    __hip_bfloat16 h = __float2bfloat16(f);
    return *reinterpret_cast<unsigned short*>(&h);
}
__device__ __forceinline__ float b2f(unsigned short u){
    __hip_bfloat16 h;
    *reinterpret_cast<unsigned short*>(&h) = u;
    return __bfloat162float(h);
}
__device__ __forceinline__ unsigned int pkbf(float lo, float hi){
    return (unsigned int)f2b(lo) | ((unsigned int)f2b(hi) << 16);
}

// async global->LDS, 16B per lane. LDS dest is wave-uniform base (+lane*16 implicit).
__device__ __forceinline__ void glds16(const void* g, void* l){
    __builtin_amdgcn_global_load_lds(
        (const __attribute__((address_space(1))) unsigned int*)g,
        (__attribute__((address_space(3))) unsigned int*)l, 16, 0, 0);
}

// ---------------- elementwise prep kernels ----------------

__global__ void k_f32bf16(const float* __restrict__ src, unsigned short* __restrict__ dst, int n4){
    int i = blockIdx.x*blockDim.x + threadIdx.x;
    if (i >= n4) return;
    const float4 v = reinterpret_cast<const float4*>(src)[i];
    u16x4 o = { f2b(v.x), f2b(v.y), f2b(v.z), f2b(v.w) };
    *reinterpret_cast<u16x4*>(dst + 4*(size_t)i) = o;
}

__global__ void k_cossin(const float* __restrict__ r, float* __restrict__ c, float* __restrict__ s, int n){
    int i = blockIdx.x*blockDim.x + threadIdx.x;
    if (i >= n) return;
    float v = r[i];
    c[i] = cosf(v);
    s[i] = sinf(v);
}

// RoPE in-place on Q and K sections of qkv [MROWS][6144] bf16
__global__ void k_rope(unsigned short* __restrict__ qkv,
                       const float* __restrict__ ct, const float* __restrict__ st){
    const int idx = blockIdx.x*blockDim.x + threadIdx.x;
    const int d = idx & 63;
    const int h = (idx >> 6) & (HEADS-1);
    const int l = (idx >> 10) & (SEQ-1);
    const int b = idx >> 21;
    const float c0 = ct[l*HD + d],      s0 = st[l*HD + d];
    const float c1 = ct[l*HD + d + 64], s1 = st[l*HD + d + 64];
    unsigned short* row = qkv + (size_t)(b*SEQ + l)*QKVN + h*HD;
    {   // Q
        float x1 = b2f(row[d]), x2 = b2f(row[d+64]);
        row[d]    = f2b(x1*c0 - x2*s0);
        row[d+64] = f2b(x2*c1 + x1*s1);
    }
    {   // K
        unsigned short* kr = row + DIMS;
        float x1 = b2f(kr[d]), x2 = b2f(kr[d+64]);
        kr[d]    = f2b(x1*c0 - x2*s0);
        kr[d+64] = f2b(x2*c1 + x1*s1);
    }
}

// V transpose: qkv V section [b][l][h*128+d] -> vt[(b*16+h)*128 + d][l]
__global__ void k_vtrans(const unsigned short* __restrict__ qkv, unsigned short* __restrict__ vt){
    __shared__ unsigned short t[64*68];
    const int lt = blockIdx.x;
    const int dt = blockIdx.y;
    const int bh = blockIdx.z;
    const int b = bh >> 4, h = bh & 15;
    const int tid = threadIdx.x;
    const int l0 = lt << 6;
    #pragma unroll
    for (int it = 0; it < 4; ++it){
        const int c = tid + (it<<8);
        const int l = c >> 4;
        const int d4 = (c & 15) << 2;
        const u16x4 v = *reinterpret_cast<const u16x4*>(
            qkv + (size_t)(b*SEQ + l0 + l)*QKVN + 2*DIMS + h*HD + (dt<<6) + d4);
        *reinterpret_cast<u16x4*>(&t[l*68 + d4]) = v;
    }
    __syncthreads();
    #pragma unroll
    for (int it = 0; it < 4; ++it){
        const int c = tid + (it<<8);
        const int d = c >> 4;
        const int l4 = (c & 15) << 2;
        u16x4 o = { t[(l4+0)*68 + d], t[(l4+1)*68 + d], t[(l4+2)*68 + d], t[(l4+3)*68 + d] };
        *reinterpret_cast<u16x4*>(&vt[((size_t)bh*HD + (dt<<6) + d)*SEQ + l0 + l4]) = o;
    }
}

// ---------------- 128x128 GEMM (m97 structure) — used for output projection ----------------

template<int FINAL>
__global__ __launch_bounds__(256) void k_gemm_bt(
    const unsigned short* __restrict__ A, const unsigned short* __restrict__ B,
    void* __restrict__ C, const float* __restrict__ bias, int M, int N, int K)
{
    __shared__ unsigned short lA[128*64];
    __shared__ unsigned short lB[128*64];
    const int tid  = threadIdx.x;
    const int lane = tid & 63;
    const int wave = tid >> 6;

    const int nbx = N >> 7;
    const int nwg = gridDim.x;
    const int cpx = nwg >> 3;
    const int bid = blockIdx.x;
    const int wg  = (bid & 7)*cpx + (bid >> 3);
    const int m0 = (wg / nbx) << 7;
    const int n0 = (wg % nbx) << 7;

    const int wr = (wave >> 1) << 6;
    const int wc = (wave & 1) << 6;

    f32x4 acc[4][4] = {};

    const int srow_base = (wave<<3) + (lane>>3);
    const int schunk = lane & 7;

    for (int k0 = 0; k0 < K; k0 += 64){
        #pragma unroll
        for (int i = 0; i < 4; ++i){
            const int row  = (i<<5) + srow_base;
            const int scol = k0 + ((schunk ^ (row & 7)) << 3);
            glds16(A + (size_t)(m0 + row)*K + scol, &lA[((i<<5) + (wave<<3)) << 6]);
            glds16(B + (size_t)(n0 + row)*K + scol, &lB[((i<<5) + (wave<<3)) << 6]);
        }
        __syncthreads();
        #pragma unroll
        for (int ks = 0; ks < 2; ++ks){
            bf16x8 af[4], bfr[4];
            const int colbase = (ks<<5) + ((lane>>4)<<3);
            #pragma unroll
            for (int mi = 0; mi < 4; ++mi){
                const int row = wr + (mi<<4) + (lane & 15);
                af[mi] = *reinterpret_cast<const bf16x8*>(&lA[(row<<6) + (colbase ^ ((row&7)<<3))]);
            }
            #pragma unroll
            for (int ni = 0; ni < 4; ++ni){
                const int row = wc + (ni<<4) + (lane & 15);
                bfr[ni] = *reinterpret_cast<const bf16x8*>(&lB[(row<<6) + (colbase ^ ((row&7)<<3))]);
            }
            #pragma unroll
            for (int mi = 0; mi < 4; ++mi)
                #pragma unroll
                for (int ni = 0; ni < 4; ++ni)
                    acc[mi][ni] = __builtin_amdgcn_mfma_f32_16x16x32_bf16(af[mi], bfr[ni], acc[mi][ni], 0, 0, 0);
        }
        __syncthreads();
    }

    const int r0 = (lane >> 4) << 2;
    const int cn = lane & 15;
    #pragma unroll
    for (int mi = 0; mi < 4; ++mi)
        #pragma unroll
        for (int r = 0; r < 4; ++r){
            const int gm = m0 + wr + (mi<<4) + r0 + r;
            #pragma unroll
            for (int ni = 0; ni < 4; ++ni){
                const int gn = n0 + wc + (ni<<4) + cn;
                const float v = acc[mi][ni][r];
                if (FINAL)
                    reinterpret_cast<float*>(C)[(size_t)gm*N + gn] = v + bias[gn];
                else
                    reinterpret_cast<unsigned short*>(C)[(size_t)gm*N + gn] = f2b(v);
            }
        }
}

// ---------------- 256x256 8-phase GEMM (T3+T4+T5) — used for QKV projection ----------------
// C[M][N] = A[M][K] * B[N][K]^T, bf16 out. BK=64, 8 waves (2M x 4N), dbuf LDS, counted vmcnt.
//
// Chunks per K-tile t: A0/A1 = A rows [m0+half*128, +128), B0/B1 likewise; each chunk
// staged as 2 glds16/lane into region lX[(t&1)][half] (XOR-swizzled via pre-swizzled source).
// Phase->quadrant: P0=(0,0) P1=(0,1) P2=(1,1) P3=(1,0); A-frags carry P0->P1, B1-frags P1->P2.
// Issue slots: P0: B0(t+1), P1: A0(t+2), P2: B1(t+2), P3: A1(t+2).
// Ledger: chunk(t) issue->first-use gap >= 3 phases; overwrite only after last read's barrier.
// Single s_waitcnt vmcnt(6) per K-tile at P3 (guarantees all of tile t+1; 3 newest chunks
// = 6 loads stay in flight). Tail: vmcnt(0) when t+2 >= nkt.

__device__ __forceinline__ void stg256(const unsigned short* __restrict__ src, int row0, int k0,
                                       unsigned short* dstregion, int wave, int lane, int Kld){
    #pragma unroll
    for (int i = 0; i < 2; ++i){
        const int r  = (i<<6) + (wave<<3) + (lane>>3);
        const int cc = (lane&7) ^ (r&7);
        glds16(src + (size_t)(row0 + r)*Kld + k0 + (cc<<3), dstregion + (((i<<6)+(wave<<3))<<6));
    }
}

__global__ __launch_bounds__(512, 2) void k_gemm256(
    const unsigned short* __restrict__ A, const unsigned short* __restrict__ B,
    unsigned short* __restrict__ C, int M, int N, int K)
{
    __shared__ unsigned short lA[2*2*128*64];   // [buf][half][128][64]
    __shared__ unsigned short lB[2*2*128*64];

    const int tid  = threadIdx.x;
    const int lane = tid & 63;
    const int wave = tid >> 6;
    const int wm   = wave >> 2;         // 0..1
    const int wn   = wave & 3;          // 0..3
    const int nkt  = K >> 6;

    const int nbx = N >> 8;
    const int nwg = gridDim.x;
    const int cpx = nwg >> 3;
    const int wg  = (blockIdx.x & 7)*cpx + (blockIdx.x >> 3);   // XCD swizzle (nwg%8==0)
    const int m0 = (wg / nbx) << 8;
    const int n0 = (wg % nbx) << 8;

    f32x4 acc[2][2][4][2] = {};

#define REGION(LX, T, H) (&LX[(((((T)&1)<<1)+(H))<<13)])
#define ST_A(T, H) do{ if ((T) < nkt) stg256(A, m0 + ((H)<<7), (T)<<6, REGION(lA,T,H), wave, lane, K); }while(0)
#define ST_B(T, H) do{ if ((T) < nkt) stg256(B, n0 + ((H)<<7), (T)<<6, REGION(lB,T,H), wave, lane, K); }while(0)

#define RD_A(DST, REG) do{ \
    _Pragma("unroll") for (int mi=0;mi<4;++mi) _Pragma("unroll") for (int ks=0;ks<2;++ks){ \
        const int rowh = (wm<<6) + (mi<<4) + (lane&15); \
        const int c8 = (ks<<2) + (lane>>4); \
        DST[mi][ks] = *reinterpret_cast<const bf16x8*>(&(REG)[(rowh<<6) + ((c8 ^ (rowh&7))<<3)]); \
    } }while(0)
#define RD_B(DST, REG) do{ \
    _Pragma("unroll") for (int ni=0;ni<2;++ni) _Pragma("unroll") for (int ks=0;ks<2;++ks){ \
        const int rowh = (wn<<5) + (ni<<4) + (lane&15); \
        const int c8 = (ks<<2) + (lane>>4); \
        DST[ni][ks] = *reinterpret_cast<const bf16x8*>(&(REG)[(rowh<<6) + ((c8 ^ (rowh&7))<<3)]); \
    } }while(0)

#define BARRIER() do{ __builtin_amdgcn_sched_barrier(0); __builtin_amdgcn_s_barrier(); \
                      __builtin_amdgcn_sched_barrier(0); }while(0)

#define MM16(QM, QN, AF, BF) do{ \
    __builtin_amdgcn_s_setprio(1); \
    _Pragma("unroll") for (int ks=0;ks<2;++ks) \
    _Pragma("unroll") for (int mi=0;mi<4;++mi) \
    _Pragma("unroll") for (int ni=0;ni<2;++ni) \
        acc[QM][QN][mi][ni] = __builtin_amdgcn_mfma_f32_16x16x32_bf16(AF[mi][ks], BF[ni][ks], acc[QM][QN][mi][ni], 0,0,0); \
    __builtin_amdgcn_s_setprio(0); \
    }while(0)

    // ---- prologue: tile0 all 4 chunks + tile1 {A0,B1,A1}; allow 3 newest outstanding ----
    ST_A(0,0); ST_B(0,1); ST_A(0,1); ST_B(0,0);
    ST_A(1,0); ST_B(1,1); ST_A(1,1);
    __builtin_amdgcn_sched_barrier(0);
    asm volatile("s_waitcnt vmcnt(6)");
    BARRIER();

    for (int t = 0; t < nkt; ++t){
        const unsigned short* rA0 = REGION(lA, t, 0);
        const unsigned short* rA1 = REGION(lA, t, 1);
        const unsigned short* rB0 = REGION(lB, t, 0);
        const unsigned short* rB1 = REGION(lB, t, 1);

        bf16x8 a0f[4][2], a1f[4][2], b0f[2][2], b1f[2][2];

        // ---- P0: quadrant (0,0) ----
        RD_A(a0f, rA0);
        RD_B(b0f, rB0);
        ST_B(t+1, 0);
        BARRIER();
        MM16(0, 0, a0f, b0f);
        BARRIER();

        // ---- P1: quadrant (0,1), carry a0f ----
        RD_B(b1f, rB1);
        ST_A(t+2, 0);
        BARRIER();
        MM16(0, 1, a0f, b1f);
        BARRIER();

        // ---- P2: quadrant (1,1), carry b1f ----
        RD_A(a1f, rA1);
        ST_B(t+2, 1);
        BARRIER();
        MM16(1, 1, a1f, b1f);
        BARRIER();

        // ---- P3: quadrant (1,0) ----
        RD_B(b0f, rB0);
        ST_A(t+2, 1);
        BARRIER();
        MM16(1, 0, a1f, b0f);
        __builtin_amdgcn_sched_barrier(0);
        if (t + 2 < nkt) { asm volatile("s_waitcnt vmcnt(6)"); }
        else             { asm volatile("s_waitcnt vmcnt(0)"); }
        BARRIER();
    }

#undef REGION
#undef ST_A
#undef ST_B
#undef RD_A
#undef RD_B
#undef BARRIER
#undef MM16

    // ---- epilogue: D layout col=lane&15, row=(lane>>4)*4+rr ----
    const int r0 = (lane >> 4) << 2;
    const int cn = lane & 15;
    #pragma unroll
    for (int qm = 0; qm < 2; ++qm)
      #pragma unroll
      for (int qn = 0; qn < 2; ++qn)
        #pragma unroll
        for (int mi = 0; mi < 4; ++mi)
          #pragma unroll
          for (int rr = 0; rr < 4; ++rr){
              const int gm = m0 + (qm<<7) + (wm<<6) + (mi<<4) + r0 + rr;
              #pragma unroll
              for (int ni = 0; ni < 2; ++ni){
                  const int gn = n0 + (qn<<7) + (wn<<5) + (ni<<4) + cn;
                  C[(size_t)gm*N + gn] = f2b(acc[qm][qn][mi][ni][rr]);
              }
          }
}

// ---------------- flash attention, swapped-operand 32x32 structure ----------------

union U8 { unsigned int w[4]; bf16x8 v; };

__global__ __launch_bounds__(512, 2) void k_attn(
    const unsigned short* __restrict__ qkv, const unsigned short* __restrict__ vt,
    unsigned short* __restrict__ aout)
{
    __shared__ unsigned short lK[2][64*128];
    __shared__ unsigned short lV[2][128*64];
    __shared__ unsigned short lO[8*32*132];

    const int tid  = threadIdx.x;
    const int lane = tid & 63;
    const int wave = tid >> 6;
    const int lq   = lane & 31;
    const int hi   = lane >> 5;
    const int bh = blockIdx.y;
    const int b = bh >> 4, h = bh & 15;
    const int q0w = (blockIdx.x << 8) + (wave << 5);

    const unsigned short* Kb = qkv + (size_t)b*SEQ*QKVN + DIMS + h*HD;
    const unsigned short* Vb = vt + (size_t)bh*HD*SEQ;

    bf16x8 qf[8];
    {
        const float qscale = 0.08838834764831845f * 1.4426950408889634f;
        const unsigned short* qp = qkv + (size_t)(b*SEQ + q0w + lq)*QKVN + h*HD + (hi<<3);
        #pragma unroll
        for (int ks = 0; ks < 8; ++ks){
            bf16x8 tv = *reinterpret_cast<const bf16x8*>(qp + (ks<<4));
            #pragma unroll
            for (int j = 0; j < 8; ++j)
                tv[j] = (short)f2b(b2f((unsigned short)tv[j]) * qscale);
            qf[ks] = tv;
        }
    }

    float m_run = -3e38f, l_run = 0.f;
    f32x16 oacc[4] = {};

    #define STAGE(pb, kv0) do { \
        _Pragma("unroll") \
        for (int i = 0; i < 2; ++i){ \
            const int kr = (wave<<3) + (i<<2) + (lane>>4); \
            glds16(Kb + (size_t)((kv0) + kr)*QKVN + (((lane&15) ^ (kr&7))<<3), \
                   &lK[pb][((wave<<3) + (i<<2))<<7]); \
            const int dr = (wave<<4) + (i<<3) + (lane>>3); \
            glds16(Vb + (size_t)dr*SEQ + (kv0) + (((lane&7) ^ (dr&7))<<3), \
                   &lV[pb][((wave<<4) + (i<<3))<<6]); \
        } \
    } while(0)

    int buf = 0;
    STAGE(0, 0);
    __syncthreads();

    for (int t = 0; t < SEQ/64; ++t){
        if (t < SEQ/64 - 1) STAGE(buf^1, (t+1)*64);

        const unsigned short* Kbuf = &lK[buf][0];
        const unsigned short* Vbuf = &lV[buf][0];

        f32x16 st0 = {}, st1 = {};
        #pragma unroll
        for (int ks = 0; ks < 8; ++ks){
            const int col = (((ks<<1) + hi) ^ (lq & 7)) << 3;
            bf16x8 k0 = *reinterpret_cast<const bf16x8*>(&Kbuf[(lq<<7) + col]);
            bf16x8 k1 = *reinterpret_cast<const bf16x8*>(&Kbuf[((32+lq)<<7) + col]);
            st0 = __builtin_amdgcn_mfma_f32_32x32x16_bf16(k0, qf[ks], st0, 0, 0, 0);
            st1 = __builtin_amdgcn_mfma_f32_32x32x16_bf16(k1, qf[ks], st1, 0, 0, 0);
        }

        float tmax = st0[0];
        #pragma unroll
        for (int r = 1; r < 16; ++r) tmax = fmaxf(tmax, st0[r]);
        #pragma unroll
        for (int r = 0; r < 16; ++r) tmax = fmaxf(tmax, st1[r]);
        tmax = fmaxf(tmax, __shfl_xor(tmax, 32));
        const float mnew = fmaxf(m_run, tmax);
        const float al = __builtin_amdgcn_exp2f(m_run - mnew);
        m_run = mnew;
        float tsum = 0.f;
        #pragma unroll
        for (int r = 0; r < 16; ++r){ float p = __builtin_amdgcn_exp2f(st0[r] - mnew); st0[r] = p; tsum += p; }
        #pragma unroll
        for (int r = 0; r < 16; ++r){ float p = __builtin_amdgcn_exp2f(st1[r] - mnew); st1[r] = p; tsum += p; }
        tsum += __shfl_xor(tsum, 32);
        l_run = l_run*al + tsum;
        #pragma unroll
        for (int dt = 0; dt < 4; ++dt) oacc[dt] *= al;

        bf16x8 pf[4];
        #define MAKEPF(dA, dB, SV) do { \
            unsigned int a0 = pkbf(SV[0],SV[1]),  b0 = pkbf(SV[2],SV[3]); \
            unsigned int c0 = pkbf(SV[4],SV[5]),  d0 = pkbf(SV[6],SV[7]); \
            unsigned int a1 = pkbf(SV[8],SV[9]),  b1 = pkbf(SV[10],SV[11]); \
            unsigned int c1 = pkbf(SV[12],SV[13]),d1 = pkbf(SV[14],SV[15]); \
            unsigned int ax0 = __shfl_xor(a0,32), bx0 = __shfl_xor(b0,32); \
            unsigned int cx0 = __shfl_xor(c0,32), dx0 = __shfl_xor(d0,32); \
            unsigned int ax1 = __shfl_xor(a1,32), bx1 = __shfl_xor(b1,32); \
            unsigned int cx1 = __shfl_xor(c1,32), dx1 = __shfl_xor(d1,32); \
            U8 u; \
            u.w[0] = hi ? cx0 : a0;  u.w[1] = hi ? dx0 : b0; \
            u.w[2] = hi ? c0 : ax0;  u.w[3] = hi ? d0 : bx0; \
            dA = u.v; \
            u.w[0] = hi ? cx1 : a1;  u.w[1] = hi ? dx1 : b1; \
            u.w[2] = hi ? c1 : ax1;  u.w[3] = hi ? d1 : bx1; \
            dB = u.v; \
        } while(0)
        MAKEPF(pf[0], pf[1], st0);
        MAKEPF(pf[2], pf[3], st1);
        #undef MAKEPF

        #pragma unroll
        for (int dt = 0; dt < 4; ++dt){
            const int rowv = (dt<<5) + lq;
            #pragma unroll
            for (int f = 0; f < 4; ++f){
                const int col = (((f<<1) + hi) ^ (lq & 7)) << 3;
                bf16x8 vf = *reinterpret_cast<const bf16x8*>(&Vbuf[(rowv<<6) + col]);
                oacc[dt] = __builtin_amdgcn_mfma_f32_32x32x16_bf16(vf, pf[f], oacc[dt], 0, 0, 0);
            }
        }

        __syncthreads();
        buf ^= 1;
    }
    #undef STAGE

    const float rl = 1.0f / l_run;
    unsigned short* oL = lO + wave*(32*132);
    #pragma unroll
    for (int dt = 0; dt < 4; ++dt)
        #pragma unroll
        for (int g = 0; g < 4; ++g){
            u16x4 w = { f2b(oacc[dt][g*4+0]*rl), f2b(oacc[dt][g*4+1]*rl),
                        f2b(oacc[dt][g*4+2]*rl), f2b(oacc[dt][g*4+3]*rl) };
            *reinterpret_cast<u16x4*>(&oL[lq*132 + (dt<<5) + (hi<<2) + (g<<3)]) = w;
        }
    #pragma unroll
    for (int i = 0; i < 16; ++i){
        const int q = (i<<1) + hi;
        u16x4 w = *reinterpret_cast<const u16x4*>(&oL[q*132 + (lq<<2)]);
        *reinterpret_cast<u16x4*>(&aout[(size_t)(b*SEQ + q0w + q)*DIMS + h*HD + (lq<<2)]) = w;
    }
}

// ---------------- launcher ----------------

extern "C" void kernel_launch(void* const* d_in, const int* in_sizes, int n_in,
                              void* d_out, int out_size, void* d_ws, size_t ws_size,
                              hipStream_t stream)
{
    const float* x    = (const float*)d_in[0];
    const float* rope = (const float*)d_in[1];
    const float* wq   = (const float*)d_in[2];
    const float* wk   = (const float*)d_in[3];
    const float* wv   = (const float*)d_in[4];
    const float* wo   = (const float*)d_in[5];
    const float* bo   = (const float*)d_in[6];
    float* out = (float*)d_out;

    char* ws = (char*)d_ws;
    unsigned short* x_bf   = (unsigned short*)(ws + 0);            // 16.8 MB
    unsigned short* wqkv   = (unsigned short*)(ws + 16777216);     // 25.2 MB
    unsigned short* wo_bf  = (unsigned short*)(ws + 41943040);     // 8.4 MB
    float*          cos_t  = (float*)(ws + 50331648);              // 1 MB
    float*          sin_t  = (float*)(ws + 51380224);              // 1 MB
    unsigned short* qkv    = (unsigned short*)(ws + 52428800);     // 50.3 MB
    unsigned short* vt     = (unsigned short*)(ws + 16777216);     // alias wqkv
    unsigned short* a_out  = (unsigned short*)(ws + 0);            // alias x_bf

    k_f32bf16<<<8192, 256, 0, stream>>>(x,  x_bf,              2097152);
    k_f32bf16<<<4096, 256, 0, stream>>>(wq, wqkv,              1048576);
    k_f32bf16<<<4096, 256, 0, stream>>>(wk, wqkv + 4194304,    1048576);
    k_f32bf16<<<4096, 256, 0, stream>>>(wv, wqkv + 8388608,    1048576);
    k_f32bf16<<<4096, 256, 0, stream>>>(wo, wo_bf,             1048576);
    k_cossin <<<1024, 256, 0, stream>>>(rope, cos_t, sin_t, SEQ*HD);

    // QKV projection: 256x256 8-phase kernel, grid 16x24 = 384 (384%8==0 for XCD swizzle)
    k_gemm256<<<(MROWS/256)*(QKVN/256), 512, 0, stream>>>(x_bf, wqkv, qkv, MROWS, QKVN, DIMS);

    k_rope<<<16384, 256, 0, stream>>>(qkv, cos_t, sin_t);

    k_vtrans<<<dim3(SEQ/64, HD/64, BATCH*HEADS), 256, 0, stream>>>(qkv, vt);

    k_attn<<<dim3(SEQ/256, BATCH*HEADS), 512, 0, stream>>>(qkv, vt, a_out);

    // output projection + bias (128^2 kernel: 256 blocks = full CU coverage)
    k_gemm_bt<1><<<(MROWS/128)*(DIMS/128), 256, 0, stream>>>(a_out, wo_bf, out, bo, MROWS, DIMS, DIMS);
}